// Round 2
// baseline (538.721 us; speedup 1.0000x reference)
//
#include <hip/hip_runtime.h>

#define NF 128
#define NGRAPHS 64
#define NCLS 10
#define NPARTS 256         // dst partitions, 512 nodes each (n <= 131072)
#define PART_SHIFT 9
#define PART_NODES 512
#define PART_CAP 9216      // mean 6250 + ~37 sigma slack
#define SPLIT_TILE 4096
#define AS_STRIDE 136      // bf16 elems per LDS A-row (128 + 8 pad)
#define SRC_BITS 17        // src < 2^17 (n <= 131072); record = dlocal<<17 | src

#define NSLICE 8           // feature slices == XCD count; slice = blockIdx % 8
#define SL 16              // cols per slice (32 B, 3.2 MB table slice < 4 MB L2)
#define AGG_TILE 32        // dst nodes per agg_slice block

typedef __attribute__((ext_vector_type(8))) short bf16x8;          // MFMA frag
typedef __attribute__((ext_vector_type(4))) float f32x4;
typedef __attribute__((ext_vector_type(8))) unsigned short u16x8;  // 16B row chunk

__device__ __forceinline__ float bf2f(unsigned short u) {
    union { unsigned int i; float f; } v; v.i = ((unsigned int)u) << 16; return v.f;
}
__device__ __forceinline__ unsigned short f2bf(float f) {
    union { float f; unsigned int i; } v; v.f = f;
    unsigned int lsb = (v.i >> 16) & 1;
    v.i += 0x7fffu + lsb;                 // RNE
    return (unsigned short)(v.i >> 16);
}

// ---------------------------------------------------------------------------
// Fused prep + split (register-staged). gcur atomic reservation + scattered
// per-partition flush. featbf is written SLICE-MAJOR [8][n][16] so each XCD's
// gather slice is a contiguous, L2-resident 3.2 MB region.
// ---------------------------------------------------------------------------
__global__ __launch_bounds__(256) void split_prep_kernel(
    const int* __restrict__ src, const int* __restrict__ dst,
    unsigned int* __restrict__ records, int* __restrict__ gcur,
    const float* __restrict__ feat, unsigned short* __restrict__ featbf,
    const float* __restrict__ W1, const float* __restrict__ W2,
    unsigned short* __restrict__ Wt1, unsigned short* __restrict__ Wt2,
    float* __restrict__ sums, int ne, int nv4) {
    __shared__ unsigned int stage[SPLIT_TILE];  // 16 KB
    __shared__ int hcnt[NPARTS];
    __shared__ int hscan[NPARTS];
    __shared__ int hcur[NPARTS];
    __shared__ int hg[NPARTS];
    int t = threadIdx.x;
    int gtid = blockIdx.x * 256 + t;
    int nthreads = gridDim.x * 256;
    int n_nodes = nv4 >> 5;                    // nv4 = n * 32

    // ---- prep (grid-stride over all blocks): fp32 -> bf16, slice-major ----
    for (int i = gtid; i < nv4; i += nthreads) {
        float4 v = ((const float4*)feat)[i];
        ushort4 o;
        o.x = f2bf(v.x); o.y = f2bf(v.y); o.z = f2bf(v.z); o.w = f2bf(v.w);
        int node = i >> 5;           // 32 float4 per 128-col row
        int q4 = i & 31;
        int s = q4 >> 2;             // slice 0..7
        int cc = (q4 & 3) * 4;       // col within slice
        *(ushort4*)(featbf + ((size_t)s * n_nodes + node) * SL + cc) = o;
    }
    for (int i = gtid; i < 2 * NF * NF; i += nthreads) {
        const float* W = (i < NF * NF) ? W1 : W2;
        unsigned short* Wt = (i < NF * NF) ? Wt1 : Wt2;
        int id = i & (NF * NF - 1);
        int f = id >> 7;
        int k = id & 127;
        Wt[f * NF + k] = f2bf(W[k * NF + f]);
    }
    for (int i = gtid; i < NGRAPHS * NF; i += nthreads) sums[i] = 0.f;

    // ---- split ----
    int tile0 = blockIdx.x * SPLIT_TILE;
    int cnt = min(SPLIT_TILE, ne - tile0);
    if (cnt <= 0) return;
    hcnt[t] = 0;
    __syncthreads();
    // pass 1: load (dst,src) into registers + histogram
    int dv[16], sv[16];
#pragma unroll
    for (int k2 = 0; k2 < 16; ++k2) {
        int i = k2 * 256 + t;
        if (i < cnt) {
            dv[k2] = dst[tile0 + i];
            sv[k2] = src[tile0 + i];
            atomicAdd(&hcnt[dv[k2] >> PART_SHIFT], 1);
        }
    }
    __syncthreads();
    // inclusive Hillis-Steele scan of 256 counters
    hscan[t] = hcnt[t];
    __syncthreads();
    for (int off = 1; off < NPARTS; off <<= 1) {
        int v = (t >= off) ? hscan[t - off] : 0;
        __syncthreads();
        hscan[t] += v;
        __syncthreads();
    }
    hcur[t] = hscan[t] - hcnt[t];
    hg[t] = hcnt[t] ? atomicAdd(&gcur[t], hcnt[t]) : 0;
    __syncthreads();
    // pass 2: place packed records from registers
#pragma unroll
    for (int k2 = 0; k2 < 16; ++k2) {
        int i = k2 * 256 + t;
        if (i < cnt) {
            int d = dv[k2];
            int pos = atomicAdd(&hcur[d >> PART_SHIFT], 1);
            stage[pos] = (((unsigned int)(d & (PART_NODES - 1))) << SRC_BITS)
                         | (unsigned int)sv[k2];
        }
    }
    __syncthreads();
    // flush: quarter-wave (16 lanes) per partition, 16 partitions concurrent
    int grp = t >> 4;
    int lt = t & 15;
    for (int p = grp; p < NPARTS; p += 16) {
        int c = hcnt[p];
        if (c == 0) continue;
        int b = hscan[p] - c;
        int g = hg[p];
        if (g + c > PART_CAP) c = max(0, PART_CAP - g);   // never in practice
        unsigned int* outp = records + (size_t)p * PART_CAP + g;
        for (int i = lt; i < c; i += 16) outp[i] = stage[b + i];
    }
}

// ---------------------------------------------------------------------------
// Per-partition CSR build with LDS record cache (unchanged).
// ---------------------------------------------------------------------------
__global__ __launch_bounds__(256) void build_kernel(
    const unsigned int* __restrict__ records, const int* __restrict__ gcur,
    int* __restrict__ offs, int* __restrict__ eid, int n) {
    __shared__ int deg[PART_NODES];       // 2 KB; becomes cursor after scan
    __shared__ int ps[NPARTS];            // 1 KB
    __shared__ int wsum[4];
    __shared__ unsigned int rc[PART_CAP]; // 36 KB record cache
    int t = threadIdx.x;
    int p = blockIdx.x;

    // partition-base scan (inclusive)
    ps[t] = min(gcur[t], PART_CAP);
    __syncthreads();
    for (int off = 1; off < NPARTS; off <<= 1) {
        int v = (t >= off) ? ps[t - off] : 0;
        __syncthreads();
        ps[t] += v;
        __syncthreads();
    }
    int L = min(gcur[p], PART_CAP);
    int base_g = ps[p] - L;
    if (p == 0 && t == 0) offs[n] = ps[NPARTS - 1];

    int lo = p << PART_SHIFT;
    int nn = min(n - lo, PART_NODES);
    if (nn <= 0) return;

    deg[t] = 0;
    deg[t + 256] = 0;
    __syncthreads();

    const unsigned int* rp = records + (size_t)p * PART_CAP;
    for (int i = t; i < L; i += 256) {
        unsigned int r = rp[i];
        rc[i] = r;
        atomicAdd(&deg[r >> SRC_BITS], 1);
    }
    __syncthreads();

    // block exclusive scan over deg[0..512) (2 elems/thread)
    int v0 = deg[2 * t];
    int v1 = deg[2 * t + 1];
    int tsum = v0 + v1;
    int lane = t & 63, w = t >> 6;
    int sc = tsum;
    for (int off = 1; off < 64; off <<= 1) {
        int u = __shfl_up(sc, off, 64);
        if (lane >= off) sc += u;
    }
    if (lane == 63) wsum[w] = sc;
    __syncthreads();
    if (t == 0) {
        int a = 0;
        for (int k = 0; k < 4; ++k) { int v = wsum[k]; wsum[k] = a; a += v; }
    }
    __syncthreads();
    int run = sc - tsum + wsum[w];
    deg[2 * t] = run;
    if (2 * t < nn) offs[lo + 2 * t] = base_g + run;
    run += v0;
    deg[2 * t + 1] = run;
    if (2 * t + 1 < nn) offs[lo + 2 * t + 1] = base_g + run;
    __syncthreads();

    // fill eid from the LDS cache
    for (int i = t; i < L; i += 256) {
        unsigned int r = rc[i];
        int pos = atomicAdd(&deg[r >> SRC_BITS], 1);
        eid[base_g + pos] = (int)(r & ((1u << SRC_BITS) - 1));
    }
}

// ---------------------------------------------------------------------------
// Slice-gather aggregation. slice = blockIdx % 8 rides the measured XCD
// round-robin (m09): each XCD gathers only its own contiguous 3.2 MB slice,
// which stays resident in its 4 MB L2 -> compulsory fetch drops 177 -> ~25.6
// MB (+ streamed eid). Any slice<->XCD bijection works; identity not needed.
// Half-wave (32 lanes) owns one node: 16 edge slots x 2 lanes x 16 B = full
// 32 B slice per edge. eid/offs are nontemporal so the stream does not evict
// the resident slice.
// ---------------------------------------------------------------------------
__global__ __launch_bounds__(256) void agg_slice(
    const unsigned short* __restrict__ xs,   // [8][n][SL] slice-major
    const int* __restrict__ offs, const int* __restrict__ eid,
    unsigned short* __restrict__ out,        // [8][n][SL] slice-major
    int n) {
    __shared__ unsigned short ob[AGG_TILE * SL];   // 1 KB staging
    int b = blockIdx.x;
    int s = b & 7;
    int node0 = (b >> 3) * AGG_TILE;
    const unsigned short* xb = xs + (size_t)s * n * SL;
    int t = threadIdx.x;
    int wave = t >> 6;
    int lane = t & 63;
    int hw = lane >> 5;        // half-wave
    int l = lane & 31;
    int slot = l >> 1;         // edge slot 0..15
    int half = l & 1;          // 16B half of the 32B slice

#pragma unroll
    for (int r = 0; r < AGG_TILE / 8; ++r) {
        int node = node0 + r * 8 + wave * 2 + hw;
        float acc[8] = {0.f, 0.f, 0.f, 0.f, 0.f, 0.f, 0.f, 0.f};
        if (node < n) {
            int beg = __builtin_nontemporal_load(offs + node);
            int end = __builtin_nontemporal_load(offs + node + 1);
            for (int j = beg + slot; j < end; j += 16) {
                int srcv = __builtin_nontemporal_load(eid + j);
                u16x8 v = *(const u16x8*)(xb + (size_t)srcv * SL + half * 8);
#pragma unroll
                for (int k = 0; k < 8; ++k) acc[k] += bf2f(v[k]);
            }
        }
        // reduce across the 16 slots (stays within the half-wave: masks < 32)
#pragma unroll
        for (int m = 2; m <= 16; m <<= 1) {
#pragma unroll
            for (int k = 0; k < 8; ++k) acc[k] += __shfl_xor(acc[k], m, 64);
        }
        if (slot == 0) {
            u16x8 o;
#pragma unroll
            for (int k = 0; k < 8; ++k) o[k] = f2bf(acc[k]);
            *(u16x8*)(&ob[(r * 8 + wave * 2 + hw) * SL + half * 8]) = o;
        }
    }
    __syncthreads();
    // coalesced 1 KB flush of the block's contiguous [node0..node0+32)x[16]
    int nrem = n - node0;
    if (nrem > AGG_TILE) nrem = AGG_TILE;
    if (nrem > 0) {
        int cu16 = nrem * SL;
        int i = t * 2;
        if (i < cu16) {
            unsigned int w = *(const unsigned int*)(&ob[i]);
            *(unsigned int*)(out + ((size_t)s * n + node0) * SL + i) = w;
        }
    }
}

// ---------------------------------------------------------------------------
// Dense MFMA GEMM on aggregated features (slice-major in/out), IN-PLACE:
// each block reads exactly the bytes it later writes (its 16 nodes, all 8
// slices), reads complete before the barrier -> safe, zero extra workspace.
// ---------------------------------------------------------------------------
__global__ __launch_bounds__(256) void gemm_h1(
    unsigned short* __restrict__ buf,        // [8][n][SL]; agg in, h out
    const unsigned short* __restrict__ Wt, const float* __restrict__ bias,
    int n) {
    __shared__ unsigned short As[16 * AS_STRIDE];
    int t = threadIdx.x;
    int node_base = blockIdx.x * 16;
    {
        int s = t >> 5;
        int u = t & 31;
        int r = u >> 1;
        int hc = (u & 1) * 8;
        int node = node_base + r;
        u16x8 v = {0, 0, 0, 0, 0, 0, 0, 0};
        if (node < n) v = *(const u16x8*)(buf + ((size_t)s * n + node) * SL + hc);
        *(u16x8*)(&As[r * AS_STRIDE + s * SL + hc]) = v;
    }
    __syncthreads();

    int wave = t >> 6;
    int lane = t & 63;
    int q = lane >> 4;
    int m16 = lane & 15;
    int n0 = wave * 32;
    const unsigned short* b0r = Wt + (size_t)(n0 + m16) * NF + q * 8;
    const unsigned short* b1r = b0r + 16 * NF;
    f32x4 acc0 = {0.f, 0.f, 0.f, 0.f};
    f32x4 acc1 = {0.f, 0.f, 0.f, 0.f};
#pragma unroll
    for (int kk = 0; kk < 4; ++kk) {
        bf16x8 a  = *(const bf16x8*)(&As[m16 * AS_STRIDE + kk * 32 + q * 8]);
        bf16x8 b0 = *(const bf16x8*)(b0r + kk * 32);
        bf16x8 b1 = *(const bf16x8*)(b1r + kk * 32);
        acc0 = __builtin_amdgcn_mfma_f32_16x16x32_bf16(a, b0, acc0, 0, 0, 0);
        acc1 = __builtin_amdgcn_mfma_f32_16x16x32_bf16(a, b1, acc1, 0, 0, 0);
    }
    float bias0 = bias[n0 + m16];
    float bias1 = bias[n0 + 16 + m16];
#pragma unroll
    for (int r = 0; r < 4; ++r) {
        int node = node_base + q * 4 + r;
        if (node >= n) break;
        buf[((size_t)(2 * wave) * n + node) * SL + m16] =
            f2bf(fmaxf(acc0[r] + bias0, 0.f));
        buf[((size_t)(2 * wave + 1) * n + node) * SL + m16] =
            f2bf(fmaxf(acc1[r] + bias1, 0.f));
    }
}

// ---------------------------------------------------------------------------
// Dense MFMA GEMM (layer 2) + pool epilogue. Reads slice-major agg; writes
// only the per-graph sums (atomics). No device fences.
// ---------------------------------------------------------------------------
__global__ __launch_bounds__(256) void gemm_h2_pool(
    const unsigned short* __restrict__ buf,  // [8][n][SL] agg2
    const unsigned short* __restrict__ Wt, const float* __restrict__ bias,
    const int* __restrict__ gid, float* __restrict__ sums, int n) {
    __shared__ unsigned short As[16 * AS_STRIDE];
    __shared__ float hblk[16][NF];
    int t = threadIdx.x;
    int node_base = blockIdx.x * 16;
    {
        int s = t >> 5;
        int u = t & 31;
        int r = u >> 1;
        int hc = (u & 1) * 8;
        int node = node_base + r;
        u16x8 v = {0, 0, 0, 0, 0, 0, 0, 0};
        if (node < n) v = *(const u16x8*)(buf + ((size_t)s * n + node) * SL + hc);
        *(u16x8*)(&As[r * AS_STRIDE + s * SL + hc]) = v;
    }
    __syncthreads();

    int wave = t >> 6;
    int lane = t & 63;
    int q = lane >> 4;
    int m16 = lane & 15;
    int n0 = wave * 32;
    const unsigned short* b0r = Wt + (size_t)(n0 + m16) * NF + q * 8;
    const unsigned short* b1r = b0r + 16 * NF;
    f32x4 acc0 = {0.f, 0.f, 0.f, 0.f};
    f32x4 acc1 = {0.f, 0.f, 0.f, 0.f};
#pragma unroll
    for (int kk = 0; kk < 4; ++kk) {
        bf16x8 a  = *(const bf16x8*)(&As[m16 * AS_STRIDE + kk * 32 + q * 8]);
        bf16x8 b0 = *(const bf16x8*)(b0r + kk * 32);
        bf16x8 b1 = *(const bf16x8*)(b1r + kk * 32);
        acc0 = __builtin_amdgcn_mfma_f32_16x16x32_bf16(a, b0, acc0, 0, 0, 0);
        acc1 = __builtin_amdgcn_mfma_f32_16x16x32_bf16(a, b1, acc1, 0, 0, 0);
    }
    float bias0 = bias[n0 + m16];
    float bias1 = bias[n0 + 16 + m16];
#pragma unroll
    for (int r = 0; r < 4; ++r) {
        int row = q * 4 + r;
        hblk[row][n0 + m16]      = fmaxf(acc0[r] + bias0, 0.f);
        hblk[row][n0 + 16 + m16] = fmaxf(acc1[r] + bias1, 0.f);
    }
    __syncthreads();

    if (t < NF) {
        float accp = 0.f;
        int cur = -1;
        int lim = min(16, n - node_base);
        for (int i = 0; i < lim; ++i) {
            int g = gid[node_base + i];
            if (g != cur) {
                if (cur >= 0) atomicAdd(&sums[cur * NF + t], accp);
                accp = 0.f;
                cur = g;
            }
            accp += bf2f(f2bf(hblk[i][t]));    // keep bf16 rounding of h2 path
        }
        if (cur >= 0) atomicAdd(&sums[cur * NF + t], accp);
    }
}

__device__ __forceinline__ int lower_bound_i(const int* a, int n, int key) {
    int lo = 0, hi = n;
    while (lo < hi) {
        int mid = (lo + hi) >> 1;
        if (a[mid] < key) lo = mid + 1; else hi = mid;
    }
    return lo;
}

__global__ __launch_bounds__(64) void final_kernel(
    const float* __restrict__ sums, const int* __restrict__ gid, int n,
    const float* __restrict__ Wp, const float* __restrict__ bp,
    float* __restrict__ out) {
    __shared__ int range[2];
    int g = blockIdx.x;
    int c = threadIdx.x;
    if (c == 0) range[0] = lower_bound_i(gid, n, g);
    if (c == 1) range[1] = lower_bound_i(gid, n, g + 1);
    __syncthreads();
    if (c >= NCLS) return;
    float cnt = fmaxf((float)(range[1] - range[0]), 1.0f);
    float inv = 1.0f / cnt;
    float acc = bp[c];
#pragma unroll 8
    for (int k = 0; k < NF; ++k) {
        acc += sums[g * NF + k] * inv * Wp[k * NCLS + c];
    }
    out[g * NCLS + c] = acc;
}

extern "C" void kernel_launch(void* const* d_in, const int* in_sizes, int n_in,
                              void* d_out, int out_size, void* d_ws, size_t ws_size,
                              hipStream_t stream) {
    const float* feat = (const float*)d_in[0];
    const float* W1   = (const float*)d_in[1];
    const float* b1   = (const float*)d_in[2];
    const float* W2   = (const float*)d_in[3];
    const float* b2   = (const float*)d_in[4];
    const float* Wp   = (const float*)d_in[5];
    const float* bp   = (const float*)d_in[6];
    const int*   src  = (const int*)d_in[7];
    const int*   dst  = (const int*)d_in[8];
    const int*   gid  = (const int*)d_in[9];

    int ne = in_sizes[7];
    int n  = in_sizes[9];

    // Workspace (16B-aligned segments). bufA/bufB ping-pong:
    //   aggslice1: A(featbf) -> B ; gemm_h1 in-place on B ;
    //   aggslice2: B -> A          ; gemm_h2_pool reads A.
    unsigned short* bufA = (unsigned short*)d_ws;                    // n*128 u16
    unsigned short* bufB = bufA + (size_t)n * NF;                    // n*128 u16
    unsigned int* records = (unsigned int*)(bufB + (size_t)n * NF);  // 256*PART_CAP u32
    int* eid      = (int*)(records + (size_t)NPARTS * PART_CAP);     // ne
    float* sums   = (float*)(eid + ne);                              // 64*128
    int* gcur     = (int*)(sums + NGRAPHS * NF);                     // 256
    unsigned short* Wt1 = (unsigned short*)(gcur + NPARTS);          // 128*128
    unsigned short* Wt2 = Wt1 + NF * NF;                             // 128*128
    int* offs     = (int*)(Wt2 + NF * NF);                           // n+1

    int nv4 = n * NF / 4;
    int splitblocks = (ne + SPLIT_TILE - 1) / SPLIT_TILE;
    int buildblocks = (n + PART_NODES - 1) >> PART_SHIFT;
    int aggblocks = NSLICE * ((n + AGG_TILE - 1) / AGG_TILE);
    int gemmblocks = (n + 15) / 16;

    hipMemsetAsync(gcur, 0, NPARTS * sizeof(int), stream);
    split_prep_kernel<<<splitblocks, 256, 0, stream>>>(
        src, dst, records, gcur, feat, bufA, W1, W2, Wt1, Wt2, sums, ne, nv4);
    build_kernel<<<buildblocks, 256, 0, stream>>>(records, gcur, offs, eid, n);

    agg_slice<<<aggblocks, 256, 0, stream>>>(bufA, offs, eid, bufB, n);
    gemm_h1<<<gemmblocks, 256, 0, stream>>>(bufB, Wt1, b1, n);
    agg_slice<<<aggblocks, 256, 0, stream>>>(bufB, offs, eid, bufA, n);
    gemm_h2_pool<<<gemmblocks, 256, 0, stream>>>(bufA, Wt2, b2, gid, sums, n);
    final_kernel<<<NGRAPHS, 64, 0, stream>>>(sums, gid, n, Wp, bp, (float*)d_out);
}

// Round 3
// 315.770 us; speedup vs baseline: 1.7061x; 1.7061x over previous
//
#include <hip/hip_runtime.h>

#define NF 128
#define NGRAPHS 64
#define NCLS 10
#define NPARTS 256         // dst partitions, 512 nodes each (n <= 131072)
#define PART_SHIFT 9
#define PART_NODES 512
#define PART_CAP 9216      // mean 6250 + ~37 sigma slack
#define SPLIT_TILE 4096
#define AS_STRIDE 136      // bf16 elems per LDS A-row (128 + 8 pad)
#define SRC_BITS 17        // src < 2^17 (n <= 131072); record = dlocal<<17 | src

typedef __attribute__((ext_vector_type(8))) short bf16x8;          // MFMA frag
typedef __attribute__((ext_vector_type(4))) float f32x4;
typedef __attribute__((ext_vector_type(8))) unsigned short u16x8;  // 16B row chunk

__device__ __forceinline__ float bf2f(unsigned short u) {
    union { unsigned int i; float f; } v; v.i = ((unsigned int)u) << 16; return v.f;
}
__device__ __forceinline__ unsigned short f2bf(float f) {
    union { float f; unsigned int i; } v; v.f = f;
    unsigned int lsb = (v.i >> 16) & 1;
    v.i += 0x7fffu + lsb;                 // RNE
    return (unsigned short)(v.i >> 16);
}

// DMA one 16B-per-lane wave gather into LDS (wave-uniform lds base, per-lane
// global address). Bypasses the VGPR-return path — the round-0/1/2 counters
// show gathers plateau ~5.4 TB/s regardless of MLP depth and L2 residency,
// consistent with a per-CU outstanding-request cap on the return path.
__device__ __forceinline__ void load_lds16(const unsigned short* g,
                                           unsigned short* l) {
    __builtin_amdgcn_global_load_lds(
        (const __attribute__((address_space(1))) void*)g,
        (__attribute__((address_space(3))) void*)l, 16, 0, 0);
}

// ---------------------------------------------------------------------------
// Register-path per-node gather (round-1 form) — kept for gather_gemm2_pool
// as the in-run A/B control against the DMA-gather in gather_gemm1.
// ---------------------------------------------------------------------------
__device__ __forceinline__ void gather_node(
    const unsigned short* __restrict__ x, const int* __restrict__ offs,
    const int* __restrict__ eid, int node, int n, int c, float acc[8]) {
#pragma unroll
    for (int r = 0; r < 8; ++r) acc[r] = 0.f;
    if (node >= n) return;
    int j = offs[node];
    int end = offs[node + 1];
    for (; j + 8 <= end; j += 8) {
        int s0 = eid[j + 0], s1 = eid[j + 1], s2 = eid[j + 2], s3 = eid[j + 3];
        int s4 = eid[j + 4], s5 = eid[j + 5], s6 = eid[j + 6], s7 = eid[j + 7];
        u16x8 v0 = ((const u16x8*)(x + (size_t)s0 * NF))[c];
        u16x8 v1 = ((const u16x8*)(x + (size_t)s1 * NF))[c];
        u16x8 v2 = ((const u16x8*)(x + (size_t)s2 * NF))[c];
        u16x8 v3 = ((const u16x8*)(x + (size_t)s3 * NF))[c];
        u16x8 v4 = ((const u16x8*)(x + (size_t)s4 * NF))[c];
        u16x8 v5 = ((const u16x8*)(x + (size_t)s5 * NF))[c];
        u16x8 v6 = ((const u16x8*)(x + (size_t)s6 * NF))[c];
        u16x8 v7 = ((const u16x8*)(x + (size_t)s7 * NF))[c];
#pragma unroll
        for (int r = 0; r < 8; ++r)
            acc[r] += ((bf2f(v0[r]) + bf2f(v1[r])) + (bf2f(v2[r]) + bf2f(v3[r])))
                    + ((bf2f(v4[r]) + bf2f(v5[r])) + (bf2f(v6[r]) + bf2f(v7[r])));
    }
    if (j + 4 <= end) {
        int s0 = eid[j + 0], s1 = eid[j + 1], s2 = eid[j + 2], s3 = eid[j + 3];
        u16x8 v0 = ((const u16x8*)(x + (size_t)s0 * NF))[c];
        u16x8 v1 = ((const u16x8*)(x + (size_t)s1 * NF))[c];
        u16x8 v2 = ((const u16x8*)(x + (size_t)s2 * NF))[c];
        u16x8 v3 = ((const u16x8*)(x + (size_t)s3 * NF))[c];
#pragma unroll
        for (int r = 0; r < 8; ++r)
            acc[r] += (bf2f(v0[r]) + bf2f(v1[r])) + (bf2f(v2[r]) + bf2f(v3[r]));
        j += 4;
    }
    for (; j < end; ++j) {
        int s0 = eid[j];
        u16x8 v0 = ((const u16x8*)(x + (size_t)s0 * NF))[c];
#pragma unroll
        for (int r = 0; r < 8; ++r) acc[r] += bf2f(v0[r]);
    }
}

// ---------------------------------------------------------------------------
// Fused prep + split (register-staged, round-1 form). featbf row-major.
// ---------------------------------------------------------------------------
__global__ __launch_bounds__(256) void split_prep_kernel(
    const int* __restrict__ src, const int* __restrict__ dst,
    unsigned int* __restrict__ records, int* __restrict__ gcur,
    const float* __restrict__ feat, unsigned short* __restrict__ featbf,
    const float* __restrict__ W1, const float* __restrict__ W2,
    unsigned short* __restrict__ Wt1, unsigned short* __restrict__ Wt2,
    float* __restrict__ sums, int ne, int nv4) {
    __shared__ unsigned int stage[SPLIT_TILE];  // 16 KB
    __shared__ int hcnt[NPARTS];
    __shared__ int hscan[NPARTS];
    __shared__ int hcur[NPARTS];
    __shared__ int hg[NPARTS];
    int t = threadIdx.x;
    int gtid = blockIdx.x * 256 + t;
    int nthreads = gridDim.x * 256;

    // ---- prep (grid-stride over all blocks) ----
    for (int i = gtid; i < nv4; i += nthreads) {
        float4 v = ((const float4*)feat)[i];
        ushort4 o;
        o.x = f2bf(v.x); o.y = f2bf(v.y); o.z = f2bf(v.z); o.w = f2bf(v.w);
        ((ushort4*)featbf)[i] = o;
    }
    for (int i = gtid; i < 2 * NF * NF; i += nthreads) {
        const float* W = (i < NF * NF) ? W1 : W2;
        unsigned short* Wt = (i < NF * NF) ? Wt1 : Wt2;
        int id = i & (NF * NF - 1);
        int f = id >> 7;
        int k = id & 127;
        Wt[f * NF + k] = f2bf(W[k * NF + f]);
    }
    for (int i = gtid; i < NGRAPHS * NF; i += nthreads) sums[i] = 0.f;

    // ---- split ----
    int tile0 = blockIdx.x * SPLIT_TILE;
    int cnt = min(SPLIT_TILE, ne - tile0);
    if (cnt <= 0) return;
    hcnt[t] = 0;
    __syncthreads();
    // pass 1: load (dst,src) into registers + histogram
    int dv[16], sv[16];
#pragma unroll
    for (int k2 = 0; k2 < 16; ++k2) {
        int i = k2 * 256 + t;
        if (i < cnt) {
            dv[k2] = dst[tile0 + i];
            sv[k2] = src[tile0 + i];
            atomicAdd(&hcnt[dv[k2] >> PART_SHIFT], 1);
        }
    }
    __syncthreads();
    // inclusive Hillis-Steele scan of 256 counters
    hscan[t] = hcnt[t];
    __syncthreads();
    for (int off = 1; off < NPARTS; off <<= 1) {
        int v = (t >= off) ? hscan[t - off] : 0;
        __syncthreads();
        hscan[t] += v;
        __syncthreads();
    }
    hcur[t] = hscan[t] - hcnt[t];
    hg[t] = hcnt[t] ? atomicAdd(&gcur[t], hcnt[t]) : 0;
    __syncthreads();
    // pass 2: place packed records from registers
#pragma unroll
    for (int k2 = 0; k2 < 16; ++k2) {
        int i = k2 * 256 + t;
        if (i < cnt) {
            int d = dv[k2];
            int pos = atomicAdd(&hcur[d >> PART_SHIFT], 1);
            stage[pos] = (((unsigned int)(d & (PART_NODES - 1))) << SRC_BITS)
                         | (unsigned int)sv[k2];
        }
    }
    __syncthreads();
    // flush: quarter-wave (16 lanes) per partition, 16 partitions concurrent
    int grp = t >> 4;
    int lt = t & 15;
    for (int p = grp; p < NPARTS; p += 16) {
        int c = hcnt[p];
        if (c == 0) continue;
        int b = hscan[p] - c;
        int g = hg[p];
        if (g + c > PART_CAP) c = max(0, PART_CAP - g);   // never in practice
        unsigned int* outp = records + (size_t)p * PART_CAP + g;
        for (int i = lt; i < c; i += 16) outp[i] = stage[b + i];
    }
}

// ---------------------------------------------------------------------------
// Per-partition CSR build with LDS record cache (round-1 form).
// ---------------------------------------------------------------------------
__global__ __launch_bounds__(256) void build_kernel(
    const unsigned int* __restrict__ records, const int* __restrict__ gcur,
    int* __restrict__ offs, int* __restrict__ eid, int n) {
    __shared__ int deg[PART_NODES];       // 2 KB; becomes cursor after scan
    __shared__ int ps[NPARTS];            // 1 KB
    __shared__ int wsum[4];
    __shared__ unsigned int rc[PART_CAP]; // 36 KB record cache
    int t = threadIdx.x;
    int p = blockIdx.x;

    // partition-base scan (inclusive)
    ps[t] = min(gcur[t], PART_CAP);
    __syncthreads();
    for (int off = 1; off < NPARTS; off <<= 1) {
        int v = (t >= off) ? ps[t - off] : 0;
        __syncthreads();
        ps[t] += v;
        __syncthreads();
    }
    int L = min(gcur[p], PART_CAP);
    int base_g = ps[p] - L;
    if (p == 0 && t == 0) offs[n] = ps[NPARTS - 1];

    int lo = p << PART_SHIFT;
    int nn = min(n - lo, PART_NODES);
    if (nn <= 0) return;

    deg[t] = 0;
    deg[t + 256] = 0;
    __syncthreads();

    const unsigned int* rp = records + (size_t)p * PART_CAP;
    for (int i = t; i < L; i += 256) {
        unsigned int r = rp[i];
        rc[i] = r;
        atomicAdd(&deg[r >> SRC_BITS], 1);
    }
    __syncthreads();

    // block exclusive scan over deg[0..512) (2 elems/thread)
    int v0 = deg[2 * t];
    int v1 = deg[2 * t + 1];
    int tsum = v0 + v1;
    int lane = t & 63, w = t >> 6;
    int sc = tsum;
    for (int off = 1; off < 64; off <<= 1) {
        int u = __shfl_up(sc, off, 64);
        if (lane >= off) sc += u;
    }
    if (lane == 63) wsum[w] = sc;
    __syncthreads();
    if (t == 0) {
        int a = 0;
        for (int k = 0; k < 4; ++k) { int v = wsum[k]; wsum[k] = a; a += v; }
    }
    __syncthreads();
    int run = sc - tsum + wsum[w];
    deg[2 * t] = run;
    if (2 * t < nn) offs[lo + 2 * t] = base_g + run;
    run += v0;
    deg[2 * t + 1] = run;
    if (2 * t + 1 < nn) offs[lo + 2 * t + 1] = base_g + run;
    __syncthreads();

    // fill eid from the LDS cache
    for (int i = t; i < L; i += 256) {
        unsigned int r = rc[i];
        int pos = atomicAdd(&deg[r >> SRC_BITS], 1);
        eid[base_g + pos] = (int)(r & ((1u << SRC_BITS) - 1));
    }
}

// ---------------------------------------------------------------------------
// Fused gather + MFMA GEMM (layer 1) — DMA-gather experiment.
// Wave owns one node per i-iter; each global_load_lds stages 4 neighbor rows
// (64 lanes x 16 B) into per-wave LDS slots; up to 4 instrs (16 rows / 4 KB)
// in flight before one vmcnt(0). Accumulate via conflict-free ds_read_b32
// (lane owns 2 feature columns). Layer 2 keeps the register path as control.
// ---------------------------------------------------------------------------
__global__ __launch_bounds__(256) void gather_gemm1(
    const unsigned short* __restrict__ x, const int* __restrict__ offs,
    const int* __restrict__ eid, const unsigned short* __restrict__ Wt,
    const float* __restrict__ bias, unsigned short* __restrict__ out, int n) {
    __shared__ unsigned short As[16 * AS_STRIDE];
    __shared__ unsigned short stg[4][16][NF];   // 16 KB: 4 waves x 16 row slots
    int wave = threadIdx.x >> 6;
    int lane = threadIdx.x & 63;
    int node_base = blockIdx.x * 16;
    unsigned short* myst = &stg[wave][0][0];

    for (int i = 0; i < 4; ++i) {
        int row = wave * 4 + i;
        int node = node_base + row;
        float a0 = 0.f, a1 = 0.f;
        if (node < n) {
            int beg = offs[node];
            int end = offs[node + 1];
            for (int j0 = beg; j0 < end; j0 += 16) {
                // all prior ds_reads of these slots completed before re-staging
                asm volatile("s_waitcnt lgkmcnt(0)" ::: "memory");
                int cnt = end - j0;
                if (cnt > 16) cnt = 16;
                int nch = (cnt + 3) >> 2;
                for (int ch = 0; ch < nch; ++ch) {
                    int sj = j0 + ch * 4 + (lane >> 4);
                    int e = eid[sj < end ? sj : beg];   // clamp: row re-fetched, not summed
                    const unsigned short* gp = x + (size_t)e * NF + (lane & 15) * 8;
                    load_lds16(gp, myst + ch * 512);
                }
                asm volatile("s_waitcnt vmcnt(0)" ::: "memory");
                for (int s = 0; s < cnt; ++s) {
                    unsigned int w = *(const unsigned int*)(myst + s * NF + lane * 2);
                    a0 += bf2f((unsigned short)(w & 0xffffu));
                    a1 += bf2f((unsigned short)(w >> 16));
                }
                asm volatile("" ::: "memory");   // no reorder across rounds
            }
        }
        *(unsigned int*)(&As[row * AS_STRIDE + lane * 2]) =
            ((unsigned int)f2bf(a1) << 16) | (unsigned int)f2bf(a0);
    }
    __syncthreads();

    int q = lane >> 4;
    int m16 = lane & 15;
    int n0 = wave * 32;
    const unsigned short* b0r = Wt + (size_t)(n0 + m16) * NF + q * 8;
    const unsigned short* b1r = b0r + 16 * NF;
    f32x4 acc0 = {0.f, 0.f, 0.f, 0.f};
    f32x4 acc1 = {0.f, 0.f, 0.f, 0.f};
#pragma unroll
    for (int kk = 0; kk < 4; ++kk) {
        bf16x8 a  = *(const bf16x8*)(&As[m16 * AS_STRIDE + kk * 32 + q * 8]);
        bf16x8 b0 = *(const bf16x8*)(b0r + kk * 32);
        bf16x8 b1 = *(const bf16x8*)(b1r + kk * 32);
        acc0 = __builtin_amdgcn_mfma_f32_16x16x32_bf16(a, b0, acc0, 0, 0, 0);
        acc1 = __builtin_amdgcn_mfma_f32_16x16x32_bf16(a, b1, acc1, 0, 0, 0);
    }
    float bias0 = bias[n0 + m16];
    float bias1 = bias[n0 + 16 + m16];
#pragma unroll
    for (int r = 0; r < 4; ++r) {
        int node = node_base + q * 4 + r;
        if (node >= n) break;
        unsigned short* o = out + (size_t)node * NF;
        o[n0 + m16]      = f2bf(fmaxf(acc0[r] + bias0, 0.f));
        o[n0 + 16 + m16] = f2bf(fmaxf(acc1[r] + bias1, 0.f));
    }
}

// ---------------------------------------------------------------------------
// Fused gather + MFMA GEMM (layer 2) + pool epilogue (round-1 form, control).
// ---------------------------------------------------------------------------
__global__ __launch_bounds__(256) void gather_gemm2_pool(
    const unsigned short* __restrict__ x, const int* __restrict__ offs,
    const int* __restrict__ eid, const unsigned short* __restrict__ Wt,
    const float* __restrict__ bias, const int* __restrict__ gid,
    float* __restrict__ sums, int n) {
    __shared__ unsigned short As[16 * AS_STRIDE];
    __shared__ float hblk[16][NF];
    int wave = threadIdx.x >> 6;
    int lane = threadIdx.x & 63;
    int q = lane >> 4;
    int c = lane & 15;
    int node_base = blockIdx.x * 16;
    int row = wave * 4 + q;

    float acc[8];
    gather_node(x, offs, eid, node_base + row, n, c, acc);
    {
        u16x8 o;
#pragma unroll
        for (int r = 0; r < 8; ++r) o[r] = f2bf(acc[r]);
        *(u16x8*)(&As[row * AS_STRIDE + c * 8]) = o;
    }
    __syncthreads();

    int m16 = c;
    int n0 = wave * 32;
    const unsigned short* b0r = Wt + (size_t)(n0 + m16) * NF + q * 8;
    const unsigned short* b1r = b0r + 16 * NF;
    f32x4 acc0 = {0.f, 0.f, 0.f, 0.f};
    f32x4 acc1 = {0.f, 0.f, 0.f, 0.f};
#pragma unroll
    for (int kk = 0; kk < 4; ++kk) {
        bf16x8 a  = *(const bf16x8*)(&As[m16 * AS_STRIDE + kk * 32 + q * 8]);
        bf16x8 b0 = *(const bf16x8*)(b0r + kk * 32);
        bf16x8 b1 = *(const bf16x8*)(b1r + kk * 32);
        acc0 = __builtin_amdgcn_mfma_f32_16x16x32_bf16(a, b0, acc0, 0, 0, 0);
        acc1 = __builtin_amdgcn_mfma_f32_16x16x32_bf16(a, b1, acc1, 0, 0, 0);
    }
    float bias0 = bias[n0 + m16];
    float bias1 = bias[n0 + 16 + m16];
#pragma unroll
    for (int r = 0; r < 4; ++r) {
        int rr = q * 4 + r;
        hblk[rr][n0 + m16]      = fmaxf(acc0[r] + bias0, 0.f);
        hblk[rr][n0 + 16 + m16] = fmaxf(acc1[r] + bias1, 0.f);
    }
    __syncthreads();

    int t = threadIdx.x;
    if (t < NF) {
        float accp = 0.f;
        int cur = -1;
        int lim = min(16, n - node_base);
        for (int i = 0; i < lim; ++i) {
            int g = gid[node_base + i];
            if (g != cur) {
                if (cur >= 0) atomicAdd(&sums[cur * NF + t], accp);
                accp = 0.f;
                cur = g;
            }
            accp += bf2f(f2bf(hblk[i][t]));    // keep bf16 rounding of h2 path
        }
        if (cur >= 0) atomicAdd(&sums[cur * NF + t], accp);
    }
}

__device__ __forceinline__ int lower_bound_i(const int* a, int n, int key) {
    int lo = 0, hi = n;
    while (lo < hi) {
        int mid = (lo + hi) >> 1;
        if (a[mid] < key) lo = mid + 1; else hi = mid;
    }
    return lo;
}

__global__ __launch_bounds__(64) void final_kernel(
    const float* __restrict__ sums, const int* __restrict__ gid, int n,
    const float* __restrict__ Wp, const float* __restrict__ bp,
    float* __restrict__ out) {
    __shared__ int range[2];
    int g = blockIdx.x;
    int c = threadIdx.x;
    if (c == 0) range[0] = lower_bound_i(gid, n, g);
    if (c == 1) range[1] = lower_bound_i(gid, n, g + 1);
    __syncthreads();
    if (c >= NCLS) return;
    float cnt = fmaxf((float)(range[1] - range[0]), 1.0f);
    float inv = 1.0f / cnt;
    float acc = bp[c];
#pragma unroll 8
    for (int k = 0; k < NF; ++k) {
        acc += sums[g * NF + k] * inv * Wp[k * NCLS + c];
    }
    out[g * NCLS + c] = acc;
}

extern "C" void kernel_launch(void* const* d_in, const int* in_sizes, int n_in,
                              void* d_out, int out_size, void* d_ws, size_t ws_size,
                              hipStream_t stream) {
    const float* feat = (const float*)d_in[0];
    const float* W1   = (const float*)d_in[1];
    const float* b1   = (const float*)d_in[2];
    const float* W2   = (const float*)d_in[3];
    const float* b2   = (const float*)d_in[4];
    const float* Wp   = (const float*)d_in[5];
    const float* bp   = (const float*)d_in[6];
    const int*   src  = (const int*)d_in[7];
    const int*   dst  = (const int*)d_in[8];
    const int*   gid  = (const int*)d_in[9];

    int ne = in_sizes[7];
    int n  = in_sizes[9];

    // Workspace (16B-aligned segments):
    unsigned short* featbf = (unsigned short*)d_ws;                  // n*128 u16
    unsigned short* h1     = featbf + (size_t)n * NF;                // n*128 u16
    unsigned int* records = (unsigned int*)(h1 + (size_t)n * NF);    // 256*PART_CAP u32
    int* eid      = (int*)(records + (size_t)NPARTS * PART_CAP);     // ne
    float* sums   = (float*)(eid + ne);                              // 64*128
    int* gcur     = (int*)(sums + NGRAPHS * NF);                     // 256
    unsigned short* Wt1 = (unsigned short*)(gcur + NPARTS);          // 128*128
    unsigned short* Wt2 = Wt1 + NF * NF;                             // 128*128
    int* offs     = (int*)(Wt2 + NF * NF);                           // n+1

    int nv4 = n * NF / 4;
    int splitblocks = (ne + SPLIT_TILE - 1) / SPLIT_TILE;
    int buildblocks = (n + PART_NODES - 1) >> PART_SHIFT;
    int ggblocks = (n + 15) / 16;

    hipMemsetAsync(gcur, 0, NPARTS * sizeof(int), stream);
    split_prep_kernel<<<splitblocks, 256, 0, stream>>>(
        src, dst, records, gcur, feat, featbf, W1, W2, Wt1, Wt2, sums, ne, nv4);
    build_kernel<<<buildblocks, 256, 0, stream>>>(records, gcur, offs, eid, n);

    gather_gemm1<<<ggblocks, 256, 0, stream>>>(featbf, offs, eid, Wt1, b1, h1, n);
    gather_gemm2_pool<<<ggblocks, 256, 0, stream>>>(h1, offs, eid, Wt2, b2, gid, sums, n);
    final_kernel<<<NGRAPHS, 64, 0, stream>>>(sums, gid, n, Wp, bp, (float*)d_out);
}

// Round 4
// 309.596 us; speedup vs baseline: 1.7401x; 1.0199x over previous
//
#include <hip/hip_runtime.h>

#define NF 128
#define NGRAPHS 64
#define NCLS 10
#define NPARTS 256         // dst partitions, 512 nodes each (n <= 131072)
#define PART_SHIFT 9
#define PART_NODES 512
#define PART_CAP 9216      // mean 6250 + ~37 sigma slack
#define SPLIT_TILE 2048    // r4: 782 blocks (3.05/CU) fixes 1.5-blk/CU imbalance
#define AS_STRIDE 136      // bf16 elems per LDS A-row (128 + 8 pad)
#define SRC_BITS 17        // src < 2^17 (n <= 131072); record = dlocal<<17 | src

typedef __attribute__((ext_vector_type(8))) short bf16x8;          // MFMA frag
typedef __attribute__((ext_vector_type(4))) float f32x4;
typedef __attribute__((ext_vector_type(8))) unsigned short u16x8;  // 16B row chunk

__device__ __forceinline__ float bf2f(unsigned short u) {
    union { unsigned int i; float f; } v; v.i = ((unsigned int)u) << 16; return v.f;
}
__device__ __forceinline__ unsigned short f2bf(float f) {
    union { float f; unsigned int i; } v; v.f = f;
    unsigned int lsb = (v.i >> 16) & 1;
    v.i += 0x7fffu + lsb;                 // RNE
    return (unsigned short)(v.i >> 16);
}

// ---------------------------------------------------------------------------
// Register-path per-node gather (round-1 form, best measured: 76 us/layer).
// r0/r2/r3 A/B established this is at the random-256B machine rate
// (~21 GB/s/CU regardless of MLP depth, cache tier, or LDS-DMA path).
// ---------------------------------------------------------------------------
__device__ __forceinline__ void gather_node(
    const unsigned short* __restrict__ x, const int* __restrict__ offs,
    const int* __restrict__ eid, int node, int n, int c, float acc[8]) {
#pragma unroll
    for (int r = 0; r < 8; ++r) acc[r] = 0.f;
    if (node >= n) return;
    int j = offs[node];
    int end = offs[node + 1];
    for (; j + 8 <= end; j += 8) {
        int s0 = eid[j + 0], s1 = eid[j + 1], s2 = eid[j + 2], s3 = eid[j + 3];
        int s4 = eid[j + 4], s5 = eid[j + 5], s6 = eid[j + 6], s7 = eid[j + 7];
        u16x8 v0 = ((const u16x8*)(x + (size_t)s0 * NF))[c];
        u16x8 v1 = ((const u16x8*)(x + (size_t)s1 * NF))[c];
        u16x8 v2 = ((const u16x8*)(x + (size_t)s2 * NF))[c];
        u16x8 v3 = ((const u16x8*)(x + (size_t)s3 * NF))[c];
        u16x8 v4 = ((const u16x8*)(x + (size_t)s4 * NF))[c];
        u16x8 v5 = ((const u16x8*)(x + (size_t)s5 * NF))[c];
        u16x8 v6 = ((const u16x8*)(x + (size_t)s6 * NF))[c];
        u16x8 v7 = ((const u16x8*)(x + (size_t)s7 * NF))[c];
#pragma unroll
        for (int r = 0; r < 8; ++r)
            acc[r] += ((bf2f(v0[r]) + bf2f(v1[r])) + (bf2f(v2[r]) + bf2f(v3[r])))
                    + ((bf2f(v4[r]) + bf2f(v5[r])) + (bf2f(v6[r]) + bf2f(v7[r])));
    }
    if (j + 4 <= end) {
        int s0 = eid[j + 0], s1 = eid[j + 1], s2 = eid[j + 2], s3 = eid[j + 3];
        u16x8 v0 = ((const u16x8*)(x + (size_t)s0 * NF))[c];
        u16x8 v1 = ((const u16x8*)(x + (size_t)s1 * NF))[c];
        u16x8 v2 = ((const u16x8*)(x + (size_t)s2 * NF))[c];
        u16x8 v3 = ((const u16x8*)(x + (size_t)s3 * NF))[c];
#pragma unroll
        for (int r = 0; r < 8; ++r)
            acc[r] += (bf2f(v0[r]) + bf2f(v1[r])) + (bf2f(v2[r]) + bf2f(v3[r]));
        j += 4;
    }
    for (; j < end; ++j) {
        int s0 = eid[j];
        u16x8 v0 = ((const u16x8*)(x + (size_t)s0 * NF))[c];
#pragma unroll
        for (int r = 0; r < 8; ++r) acc[r] += bf2f(v0[r]);
    }
}

// ---------------------------------------------------------------------------
// Pure-streaming prep: feat f32->bf16, W transposes, sums zero, gcur zero
// (gcur consumed only by the NEXT dispatch -> safe, removes the memset).
// Decoupled from the split so it runs at full-grid balance.
// ---------------------------------------------------------------------------
__global__ __launch_bounds__(256) void prep_kernel(
    const float* __restrict__ feat, unsigned short* __restrict__ featbf,
    const float* __restrict__ W1, const float* __restrict__ W2,
    unsigned short* __restrict__ Wt1, unsigned short* __restrict__ Wt2,
    float* __restrict__ sums, int* __restrict__ gcur, int nv4) {
    int gtid = blockIdx.x * 256 + threadIdx.x;
    int nthreads = gridDim.x * 256;
    for (int i = gtid; i < nv4; i += nthreads) {
        float4 v = ((const float4*)feat)[i];
        ushort4 o;
        o.x = f2bf(v.x); o.y = f2bf(v.y); o.z = f2bf(v.z); o.w = f2bf(v.w);
        ((ushort4*)featbf)[i] = o;
    }
    for (int i = gtid; i < 2 * NF * NF; i += nthreads) {
        const float* W = (i < NF * NF) ? W1 : W2;
        unsigned short* Wt = (i < NF * NF) ? Wt1 : Wt2;
        int id = i & (NF * NF - 1);
        int f = id >> 7;
        int k = id & 127;
        Wt[f * NF + k] = f2bf(W[k * NF + f]);
    }
    for (int i = gtid; i < NGRAPHS * NF; i += nthreads) sums[i] = 0.f;
    if (gtid < NPARTS) gcur[gtid] = 0;
}

// ---------------------------------------------------------------------------
// Split only (register-staged histogram/scatter). 2048-edge tiles -> 782
// blocks for CU balance. gcur atomic reservation + per-partition flush.
// ---------------------------------------------------------------------------
__global__ __launch_bounds__(256) void split_kernel(
    const int* __restrict__ src, const int* __restrict__ dst,
    unsigned int* __restrict__ records, int* __restrict__ gcur, int ne) {
    __shared__ unsigned int stage[SPLIT_TILE];  // 8 KB
    __shared__ int hcnt[NPARTS];
    __shared__ int hscan[NPARTS];
    __shared__ int hcur[NPARTS];
    __shared__ int hg[NPARTS];
    int t = threadIdx.x;

    int tile0 = blockIdx.x * SPLIT_TILE;
    int cnt = min(SPLIT_TILE, ne - tile0);
    if (cnt <= 0) return;
    hcnt[t] = 0;
    __syncthreads();
    // pass 1: load (dst,src) into registers + histogram
    int dv[SPLIT_TILE / 256], sv[SPLIT_TILE / 256];
#pragma unroll
    for (int k2 = 0; k2 < SPLIT_TILE / 256; ++k2) {
        int i = k2 * 256 + t;
        if (i < cnt) {
            dv[k2] = dst[tile0 + i];
            sv[k2] = src[tile0 + i];
            atomicAdd(&hcnt[dv[k2] >> PART_SHIFT], 1);
        }
    }
    __syncthreads();
    // inclusive Hillis-Steele scan of 256 counters
    hscan[t] = hcnt[t];
    __syncthreads();
    for (int off = 1; off < NPARTS; off <<= 1) {
        int v = (t >= off) ? hscan[t - off] : 0;
        __syncthreads();
        hscan[t] += v;
        __syncthreads();
    }
    hcur[t] = hscan[t] - hcnt[t];
    hg[t] = hcnt[t] ? atomicAdd(&gcur[t], hcnt[t]) : 0;
    __syncthreads();
    // pass 2: place packed records from registers
#pragma unroll
    for (int k2 = 0; k2 < SPLIT_TILE / 256; ++k2) {
        int i = k2 * 256 + t;
        if (i < cnt) {
            int d = dv[k2];
            int pos = atomicAdd(&hcur[d >> PART_SHIFT], 1);
            stage[pos] = (((unsigned int)(d & (PART_NODES - 1))) << SRC_BITS)
                         | (unsigned int)sv[k2];
        }
    }
    __syncthreads();
    // flush: quarter-wave (16 lanes) per partition, 16 partitions concurrent
    int grp = t >> 4;
    int lt = t & 15;
    for (int p = grp; p < NPARTS; p += 16) {
        int c = hcnt[p];
        if (c == 0) continue;
        int b = hscan[p] - c;
        int g = hg[p];
        if (g + c > PART_CAP) c = max(0, PART_CAP - g);   // never in practice
        unsigned int* outp = records + (size_t)p * PART_CAP + g;
        for (int i = lt; i < c; i += 16) outp[i] = stage[b + i];
    }
}

// ---------------------------------------------------------------------------
// Per-partition CSR build with LDS record cache (unchanged).
// ---------------------------------------------------------------------------
__global__ __launch_bounds__(256) void build_kernel(
    const unsigned int* __restrict__ records, const int* __restrict__ gcur,
    int* __restrict__ offs, int* __restrict__ eid, int n) {
    __shared__ int deg[PART_NODES];       // 2 KB; becomes cursor after scan
    __shared__ int ps[NPARTS];            // 1 KB
    __shared__ int wsum[4];
    __shared__ unsigned int rc[PART_CAP]; // 36 KB record cache
    int t = threadIdx.x;
    int p = blockIdx.x;

    // partition-base scan (inclusive)
    ps[t] = min(gcur[t], PART_CAP);
    __syncthreads();
    for (int off = 1; off < NPARTS; off <<= 1) {
        int v = (t >= off) ? ps[t - off] : 0;
        __syncthreads();
        ps[t] += v;
        __syncthreads();
    }
    int L = min(gcur[p], PART_CAP);
    int base_g = ps[p] - L;
    if (p == 0 && t == 0) offs[n] = ps[NPARTS - 1];

    int lo = p << PART_SHIFT;
    int nn = min(n - lo, PART_NODES);
    if (nn <= 0) return;

    deg[t] = 0;
    deg[t + 256] = 0;
    __syncthreads();

    const unsigned int* rp = records + (size_t)p * PART_CAP;
    for (int i = t; i < L; i += 256) {
        unsigned int r = rp[i];
        rc[i] = r;
        atomicAdd(&deg[r >> SRC_BITS], 1);
    }
    __syncthreads();

    // block exclusive scan over deg[0..512) (2 elems/thread)
    int v0 = deg[2 * t];
    int v1 = deg[2 * t + 1];
    int tsum = v0 + v1;
    int lane = t & 63, w = t >> 6;
    int sc = tsum;
    for (int off = 1; off < 64; off <<= 1) {
        int u = __shfl_up(sc, off, 64);
        if (lane >= off) sc += u;
    }
    if (lane == 63) wsum[w] = sc;
    __syncthreads();
    if (t == 0) {
        int a = 0;
        for (int k = 0; k < 4; ++k) { int v = wsum[k]; wsum[k] = a; a += v; }
    }
    __syncthreads();
    int run = sc - tsum + wsum[w];
    deg[2 * t] = run;
    if (2 * t < nn) offs[lo + 2 * t] = base_g + run;
    run += v0;
    deg[2 * t + 1] = run;
    if (2 * t + 1 < nn) offs[lo + 2 * t + 1] = base_g + run;
    __syncthreads();

    // fill eid from the LDS cache
    for (int i = t; i < L; i += 256) {
        unsigned int r = rc[i];
        int pos = atomicAdd(&deg[r >> SRC_BITS], 1);
        eid[base_g + pos] = (int)(r & ((1u << SRC_BITS) - 1));
    }
}

// ---------------------------------------------------------------------------
// Fused gather + MFMA GEMM (layer 1), round-1 register path.
// ---------------------------------------------------------------------------
__global__ __launch_bounds__(256) void gather_gemm1(
    const unsigned short* __restrict__ x, const int* __restrict__ offs,
    const int* __restrict__ eid, const unsigned short* __restrict__ Wt,
    const float* __restrict__ bias, unsigned short* __restrict__ out, int n) {
    __shared__ unsigned short As[16 * AS_STRIDE];
    int wave = threadIdx.x >> 6;
    int lane = threadIdx.x & 63;
    int q = lane >> 4;        // node selector within wave
    int c = lane & 15;        // 16B chunk / m-index
    int node_base = blockIdx.x * 16;
    int row = wave * 4 + q;   // 0..15

    float acc[8];
    gather_node(x, offs, eid, node_base + row, n, c, acc);
    {
        u16x8 o;
#pragma unroll
        for (int r = 0; r < 8; ++r) o[r] = f2bf(acc[r]);
        *(u16x8*)(&As[row * AS_STRIDE + c * 8]) = o;
    }
    __syncthreads();

    int m16 = c;
    int n0 = wave * 32;
    const unsigned short* b0r = Wt + (size_t)(n0 + m16) * NF + q * 8;
    const unsigned short* b1r = b0r + 16 * NF;
    f32x4 acc0 = {0.f, 0.f, 0.f, 0.f};
    f32x4 acc1 = {0.f, 0.f, 0.f, 0.f};
#pragma unroll
    for (int kk = 0; kk < 4; ++kk) {
        bf16x8 a  = *(const bf16x8*)(&As[m16 * AS_STRIDE + kk * 32 + q * 8]);
        bf16x8 b0 = *(const bf16x8*)(b0r + kk * 32);
        bf16x8 b1 = *(const bf16x8*)(b1r + kk * 32);
        acc0 = __builtin_amdgcn_mfma_f32_16x16x32_bf16(a, b0, acc0, 0, 0, 0);
        acc1 = __builtin_amdgcn_mfma_f32_16x16x32_bf16(a, b1, acc1, 0, 0, 0);
    }
    float bias0 = bias[n0 + m16];
    float bias1 = bias[n0 + 16 + m16];
#pragma unroll
    for (int r = 0; r < 4; ++r) {
        int node = node_base + q * 4 + r;
        if (node >= n) break;
        unsigned short* o = out + (size_t)node * NF;
        o[n0 + m16]      = f2bf(fmaxf(acc0[r] + bias0, 0.f));
        o[n0 + 16 + m16] = f2bf(fmaxf(acc1[r] + bias1, 0.f));
    }
}

// ---------------------------------------------------------------------------
// Fused gather + MFMA GEMM (layer 2) + pool epilogue (round-1 form).
// ---------------------------------------------------------------------------
__global__ __launch_bounds__(256) void gather_gemm2_pool(
    const unsigned short* __restrict__ x, const int* __restrict__ offs,
    const int* __restrict__ eid, const unsigned short* __restrict__ Wt,
    const float* __restrict__ bias, const int* __restrict__ gid,
    float* __restrict__ sums, int n) {
    __shared__ unsigned short As[16 * AS_STRIDE];
    __shared__ float hblk[16][NF];
    int wave = threadIdx.x >> 6;
    int lane = threadIdx.x & 63;
    int q = lane >> 4;
    int c = lane & 15;
    int node_base = blockIdx.x * 16;
    int row = wave * 4 + q;

    float acc[8];
    gather_node(x, offs, eid, node_base + row, n, c, acc);
    {
        u16x8 o;
#pragma unroll
        for (int r = 0; r < 8; ++r) o[r] = f2bf(acc[r]);
        *(u16x8*)(&As[row * AS_STRIDE + c * 8]) = o;
    }
    __syncthreads();

    int m16 = c;
    int n0 = wave * 32;
    const unsigned short* b0r = Wt + (size_t)(n0 + m16) * NF + q * 8;
    const unsigned short* b1r = b0r + 16 * NF;
    f32x4 acc0 = {0.f, 0.f, 0.f, 0.f};
    f32x4 acc1 = {0.f, 0.f, 0.f, 0.f};
#pragma unroll
    for (int kk = 0; kk < 4; ++kk) {
        bf16x8 a  = *(const bf16x8*)(&As[m16 * AS_STRIDE + kk * 32 + q * 8]);
        bf16x8 b0 = *(const bf16x8*)(b0r + kk * 32);
        bf16x8 b1 = *(const bf16x8*)(b1r + kk * 32);
        acc0 = __builtin_amdgcn_mfma_f32_16x16x32_bf16(a, b0, acc0, 0, 0, 0);
        acc1 = __builtin_amdgcn_mfma_f32_16x16x32_bf16(a, b1, acc1, 0, 0, 0);
    }
    float bias0 = bias[n0 + m16];
    float bias1 = bias[n0 + 16 + m16];
#pragma unroll
    for (int r = 0; r < 4; ++r) {
        int rr = q * 4 + r;
        hblk[rr][n0 + m16]      = fmaxf(acc0[r] + bias0, 0.f);
        hblk[rr][n0 + 16 + m16] = fmaxf(acc1[r] + bias1, 0.f);
    }
    __syncthreads();

    int t = threadIdx.x;
    if (t < NF) {
        float accp = 0.f;
        int cur = -1;
        int lim = min(16, n - node_base);
        for (int i = 0; i < lim; ++i) {
            int g = gid[node_base + i];
            if (g != cur) {
                if (cur >= 0) atomicAdd(&sums[cur * NF + t], accp);
                accp = 0.f;
                cur = g;
            }
            accp += bf2f(f2bf(hblk[i][t]));    // keep bf16 rounding of h2 path
        }
        if (cur >= 0) atomicAdd(&sums[cur * NF + t], accp);
    }
}

__device__ __forceinline__ int lower_bound_i(const int* a, int n, int key) {
    int lo = 0, hi = n;
    while (lo < hi) {
        int mid = (lo + hi) >> 1;
        if (a[mid] < key) lo = mid + 1; else hi = mid;
    }
    return lo;
}

// ---------------------------------------------------------------------------
// Final projection: wave-parallel over the 128-dim dot (was a serial 128-iter
// loop on 10 lanes). One wave per graph.
// ---------------------------------------------------------------------------
__global__ __launch_bounds__(64) void final_kernel(
    const float* __restrict__ sums, const int* __restrict__ gid, int n,
    const float* __restrict__ Wp, const float* __restrict__ bp,
    float* __restrict__ out) {
    __shared__ int range[2];
    int g = blockIdx.x;
    int lane = threadIdx.x;
    if (lane == 0) range[0] = lower_bound_i(gid, n, g);
    if (lane == 1) range[1] = lower_bound_i(gid, n, g + 1);
    __syncthreads();
    float cnt = fmaxf((float)(range[1] - range[0]), 1.0f);
    float inv = 1.0f / cnt;
    float s0 = sums[g * NF + lane] * inv;
    float s1 = sums[g * NF + 64 + lane] * inv;
#pragma unroll
    for (int c = 0; c < NCLS; ++c) {
        float p = s0 * Wp[lane * NCLS + c] + s1 * Wp[(64 + lane) * NCLS + c];
#pragma unroll
        for (int m = 1; m < 64; m <<= 1) p += __shfl_xor(p, m, 64);
        if (lane == 0) out[g * NCLS + c] = p + bp[c];
    }
}

extern "C" void kernel_launch(void* const* d_in, const int* in_sizes, int n_in,
                              void* d_out, int out_size, void* d_ws, size_t ws_size,
                              hipStream_t stream) {
    const float* feat = (const float*)d_in[0];
    const float* W1   = (const float*)d_in[1];
    const float* b1   = (const float*)d_in[2];
    const float* W2   = (const float*)d_in[3];
    const float* b2   = (const float*)d_in[4];
    const float* Wp   = (const float*)d_in[5];
    const float* bp   = (const float*)d_in[6];
    const int*   src  = (const int*)d_in[7];
    const int*   dst  = (const int*)d_in[8];
    const int*   gid  = (const int*)d_in[9];

    int ne = in_sizes[7];
    int n  = in_sizes[9];

    // Workspace (16B-aligned segments):
    unsigned short* featbf = (unsigned short*)d_ws;                  // n*128 u16
    unsigned short* h1     = featbf + (size_t)n * NF;                // n*128 u16
    unsigned int* records = (unsigned int*)(h1 + (size_t)n * NF);    // 256*PART_CAP u32
    int* eid      = (int*)(records + (size_t)NPARTS * PART_CAP);     // ne
    float* sums   = (float*)(eid + ne);                              // 64*128
    int* gcur     = (int*)(sums + NGRAPHS * NF);                     // 256
    unsigned short* Wt1 = (unsigned short*)(gcur + NPARTS);          // 128*128
    unsigned short* Wt2 = Wt1 + NF * NF;                             // 128*128
    int* offs     = (int*)(Wt2 + NF * NF);                           // n+1

    int nv4 = n * NF / 4;
    int splitblocks = (ne + SPLIT_TILE - 1) / SPLIT_TILE;
    int buildblocks = (n + PART_NODES - 1) >> PART_SHIFT;
    int ggblocks = (n + 15) / 16;

    prep_kernel<<<1024, 256, 0, stream>>>(
        feat, featbf, W1, W2, Wt1, Wt2, sums, gcur, nv4);
    split_kernel<<<splitblocks, 256, 0, stream>>>(src, dst, records, gcur, ne);
    build_kernel<<<buildblocks, 256, 0, stream>>>(records, gcur, offs, eid, n);

    gather_gemm1<<<ggblocks, 256, 0, stream>>>(featbf, offs, eid, Wt1, b1, h1, n);
    gather_gemm2_pool<<<ggblocks, 256, 0, stream>>>(h1, offs, eid, Wt2, b2, gid, sums, n);
    final_kernel<<<NGRAPHS, 64, 0, stream>>>(sums, gid, n, Wp, bp, (float*)d_out);
}